// Round 15
// baseline (135.599 us; speedup 1.0000x reference)
//
#include <hip/hip_runtime.h>
#include <stdint.h>

// BCM_Linear: out = x @ W^T, W[o,k] = w[o>>6, k>>6, (o-k)&63]  (1024x1024)
// M=32768, N=1024, K=1024. bf16 MFMA compute, fp32 in/out.
// Round 15: single-pass fused GEMM combining ONLY validated components:
//  - R12 distance-2 counted-vmcnt schedule (homogeneous global_load_lds, 1
//    sync pair per K-tile) -- proven correct & 79.5us on bf16.
//  - A staged RAW fp32, FULL double-buffer (distance-2; R11's single-buffer
//    half-tile distance was its 2x cost), planes layout with bit7=row&1
//    varying (R11-proven 0-conflict) + sigma-rotated source (R11-verified
//    numerics), cvt_pk on read.
//  - B bf16 dbuf via pre-swizzled Wb (R2/R4/R12 verbatim).
//  96 KB LDS -> 1 blk/CU (R2 proved 8 waves @ 1blk sustains the plateau).

#define NTOK 32768
#define NCH  1024
#define NKT  16

typedef short bf16x8 __attribute__((ext_vector_type(8)));
typedef float f32x4  __attribute__((ext_vector_type(4)));
typedef unsigned short u16x8 __attribute__((ext_vector_type(8)));

static __device__ __forceinline__ unsigned short f2bf(float f) {
    unsigned int u = __float_as_uint(f);
    u += 0x7FFFu + ((u >> 16) & 1u);
    return (unsigned short)(u >> 16);
}

#define GLOAD16(gp, lp)                                                          \
    __builtin_amdgcn_global_load_lds(                                            \
        (const __attribute__((address_space(1))) unsigned int*)(gp),             \
        (__attribute__((address_space(3))) unsigned int*)(lp), 16, 0, 0)

// fp32x8 -> bf16x8 (RNE) via v_cvt_pk_bf16_f32 (R11-verified)
static __device__ __forceinline__ bf16x8 cvt8(f32x4 l, f32x4 h) {
    union { unsigned int w[4]; bf16x8 v; } u;
    asm("v_cvt_pk_bf16_f32 %0, %1, %2" : "=v"(u.w[0]) : "v"(l[0]), "v"(l[1]));
    asm("v_cvt_pk_bf16_f32 %0, %1, %2" : "=v"(u.w[1]) : "v"(l[2]), "v"(l[3]));
    asm("v_cvt_pk_bf16_f32 %0, %1, %2" : "=v"(u.w[2]) : "v"(h[0]), "v"(h[1]));
    asm("v_cvt_pk_bf16_f32 %0, %1, %2" : "=v"(u.w[3]) : "v"(h[2]), "v"(h[3]));
    return u.v;
}

// ---------------- kernel 1: circulant w -> dense bf16 W, pre-swizzled (proven) ----------------
__global__ void build_w_kernel(const float* __restrict__ w, unsigned short* __restrict__ Wb) {
    int i = blockIdx.x * blockDim.x + threadIdx.x;   // 0 .. 1024*128-1
    int o = i >> 7;
    int j = i & 127;
    int r = o >> 6;
    int q = j >> 3;
    const float* wrow = w + ((r * 16 + q) << 6);
    int k0 = j << 3;
    u16x8 v;
#pragma unroll
    for (int e = 0; e < 8; ++e) v[e] = f2bf(wrow[(o - (k0 + e)) & 63]);
    int js = (j & ~7) | ((j & 7) ^ (o & 7));
    *(u16x8*)(Wb + (((size_t)o) << 10) + (js << 3)) = v;
}

// ---------------- kernel 2: fused 128x128 GEMM, distance-2 counted ----------------
#define BAR() __builtin_amdgcn_s_barrier()
#define LGKM0() asm volatile("s_waitcnt lgkmcnt(0)" ::: "memory")
#define VMCNT(n) asm volatile("s_waitcnt vmcnt(" #n ")" ::: "memory")
#define SETPRIO(n) __builtin_amdgcn_s_setprio(n)
#define MFMA4(d, av, bv) d = __builtin_amdgcn_mfma_f32_16x16x32_bf16(av, bv, d, 0, 0, 0)
#define NOHOOK ((void)0)

// A stage: 128 rows x 64 fp32 = 32 KB/tile as 2 planes x [128 rows][128B],
// 4 gload16/thread (512 thr). Source carries sigma-rotation + row-XOR.
// instr i: plane = i>>1, rows = (i&1)*64 + tid>>3.
#define STAGE_A(buf, t) do {                                                     \
    const char* _s = srcA + ((t) << 8);                                          \
    char* _d = (buf) + (wv << 10);                                               \
    GLOAD16(_s,                        _d);                                      \
    GLOAD16(_s + ((size_t)64 << 12),   _d + 8192);                               \
    GLOAD16(_s + 128,                  _d + 16384);                              \
    GLOAD16(_s + 128 + ((size_t)64 << 12), _d + 24576);                          \
} while (0)

// B stage: 128 rows x 128 B = 16 KB, 2 gload16/thread (pre-swizzled Wb, R12 verbatim).
#define STAGE_B(buf, t) do {                                                     \
    const char* _s = srcB + ((t) << 7);                                          \
    char* _d = (buf) + (wv << 10);                                               \
    GLOAD16(_s, _d);                                                             \
    GLOAD16(_s + ((size_t)64 << 11), _d + 8192);                                 \
} while (0)

// One K-tile (R12 distance-2 schedule): reads(t) ; lgkm0 ; BAR ; stage(t+2 ->
// same bufs) ; MFMA ; VMCNT(6) [t+1 complete, t+2 in flight] ; BAR.
#define KSTEP2(Abuf, Bbuf, DO_STAGE, WN) do {                                    \
    bf16x8 afr[4][2], bfr[2][2];                                                 \
    _Pragma("unroll") for (int m = 0; m < 4; ++m)                                \
      _Pragma("unroll") for (int ks = 0; ks < 2; ++ks) {                         \
        f32x4 _lo = *(const f32x4*)((Abuf) + a_rd[ks][0] + m * 2048);            \
        f32x4 _hi = *(const f32x4*)((Abuf) + a_rd[ks][1] + m * 2048);            \
        afr[m][ks] = cvt8(_lo, _hi);                                             \
      }                                                                          \
    _Pragma("unroll") for (int n = 0; n < 2; ++n)                                \
      _Pragma("unroll") for (int ks = 0; ks < 2; ++ks)                           \
        bfr[n][ks] = *(const bf16x8*)((Bbuf) + b_off[ks] + n * 2048);            \
    LGKM0();                                                                     \
    BAR();                                                                       \
    DO_STAGE;                                                                    \
    SETPRIO(1);                                                                  \
    _Pragma("unroll") for (int m = 0; m < 4; ++m)                                \
      _Pragma("unroll") for (int n = 0; n < 2; ++n) {                            \
        MFMA4(acc[m][n], afr[m][0], bfr[n][0]);                                  \
        MFMA4(acc[m][n], afr[m][1], bfr[n][1]);                                  \
      }                                                                          \
    SETPRIO(0);                                                                  \
    WN;                                                                          \
    BAR();                                                                       \
} while (0)

__global__ void __launch_bounds__(512, 1) gemm_fused_kernel(const float* __restrict__ X,
                                                            const unsigned short* __restrict__ B,
                                                            float* __restrict__ C) {
    __shared__ __align__(16) char lds[98304];
    char* As0 = lds;                 // 2 planes x [128 rows][128 B] = 32 KB
    char* As1 = lds + 32768;
    char* Bs0 = lds + 65536;         // [128 rows][128 B] = 16 KB
    char* Bs1 = lds + 81920;

    int tid  = threadIdx.x;
    int lane = tid & 63;
    int wv   = tid >> 6;       // 0..7
    int wr   = wv >> 2;        // 0..1  (M: 2 x 64 rows)
    int wc   = wv & 3;         // 0..3  (N: 4 x 32 cols)

    // T1: XCD-chunked swizzle (R4/R12 verbatim; 2048 blocks)
    int cpx = gridDim.x >> 3;
    int wid = ((int)blockIdx.x & 7) * cpx + ((int)blockIdx.x >> 3);
    int tn = wid & 7, tm = wid >> 3;
    int m0 = tm * 128, n0 = tn * 128;

    // A staging source (R11-verified sigma + row-XOR form, extended to 128 rows):
    // row0 = tid>>3, g = tid&7; logical granule = sigma(g ^ (row0&7)),
    // sigma(x) = ((x&3)<<1)|(x>>2); plane at +128 B, rows +64 at +64*4096.
    int row0 = tid >> 3;
    int gx   = (tid & 7) ^ (row0 & 7);
    int lg   = ((gx & 3) << 1) | (gx >> 2);
    const char* srcA = (const char*)X + (((size_t)(m0 + row0)) << 12) + (lg << 4);

    // B staging source (pre-swizzled Wb -> linear gather, R12 verbatim)
    const char* srcB = (const char*)B + (((size_t)(n0 + (tid >> 3))) << 11) + ((tid & 7) << 4);

    // A frag reads: plane ks @ ks*16384; row = wr*64 + m*16 + (lane&15),
    // stride 128 B (bit7 = row&1 varies: R11-proven 0-conflict);
    // phys granule = (q | h<<2) ^ p -> logical 2q+h via source sigma.
    int p = lane & 7;
    int q = lane >> 4;
    int abase = (wr * 64 + (lane & 15)) * 128;
    int a_rd[2][2];
#pragma unroll
    for (int ks = 0; ks < 2; ++ks)
#pragma unroll
        for (int h = 0; h < 2; ++h)
            a_rd[ks][h] = ks * 16384 + abase + (((q | (h << 2)) ^ p) << 4);

    // B frag reads (R2/R4/R12 proven verbatim)
    int kq16 = q << 4;
    int bbase = (wc * 32 + (lane & 15)) * 128;
    int b_off[2] = { bbase + ((kq16 + 0)  ^ (p << 4)),
                     bbase + ((kq16 + 64) ^ (p << 4)) };

    f32x4 acc[4][2] = {};

    // ---- prologue: stage tiles 0 and 1 (6 gloads each); wait tile 0 ----
    STAGE_A(As0, 0); STAGE_B(Bs0, 0);
    STAGE_A(As1, 1); STAGE_B(Bs1, 1);
    VMCNT(6); BAR();

    // ---- main loop: tiles 0..13 (stage t+2 into the buffer just read) ----
    for (int t = 0; t < 12; t += 2) {
        KSTEP2(As0, Bs0, { STAGE_A(As0, t + 2); STAGE_B(Bs0, t + 2); }, VMCNT(6));
        KSTEP2(As1, Bs1, { STAGE_A(As1, t + 3); STAGE_B(Bs1, t + 3); }, VMCNT(6));
    }
    KSTEP2(As0, Bs0, { STAGE_A(As0, 14); STAGE_B(Bs0, 14); }, VMCNT(6));
    KSTEP2(As1, Bs1, { STAGE_A(As1, 15); STAGE_B(Bs1, 15); }, VMCNT(6));
    // ---- tile 14: no stage, drain tile 15 ----
    KSTEP2(As0, Bs0, NOHOOK, VMCNT(0));
    // ---- tile 15: compute only ----
    {
        bf16x8 afr[4][2], bfr[2][2];
#pragma unroll
        for (int m = 0; m < 4; ++m)
#pragma unroll
            for (int ks = 0; ks < 2; ++ks) {
                f32x4 _lo = *(const f32x4*)(As1 + a_rd[ks][0] + m * 2048);
                f32x4 _hi = *(const f32x4*)(As1 + a_rd[ks][1] + m * 2048);
                afr[m][ks] = cvt8(_lo, _hi);
            }
#pragma unroll
        for (int n = 0; n < 2; ++n)
#pragma unroll
            for (int ks = 0; ks < 2; ++ks)
                bfr[n][ks] = *(const bf16x8*)(Bs1 + b_off[ks] + n * 2048);
        LGKM0();
        SETPRIO(1);
#pragma unroll
        for (int m = 0; m < 4; ++m)
#pragma unroll
            for (int n = 0; n < 2; ++n) {
                MFMA4(acc[m][n], afr[m][0], bfr[n][0]);
                MFMA4(acc[m][n], afr[m][1], bfr[n][1]);
            }
        SETPRIO(0);
    }

    // epilogue (R12 verbatim): C/D layout col = lane&15, row = (lane>>4)*4 + j
    float* Cp = C + ((size_t)(m0 + wr * 64)) * NCH + n0 + wc * 32;
    int cc = lane & 15;
    int rr = (lane >> 4) << 2;
#pragma unroll
    for (int m = 0; m < 4; ++m)
#pragma unroll
        for (int j = 0; j < 4; ++j) {
            float* rowp = Cp + ((size_t)(m * 16 + rr + j)) * NCH;
#pragma unroll
            for (int n = 0; n < 2; ++n)
                rowp[n * 16 + cc] = acc[m][n][j];
        }
}

// ---------------- fallback (ws too small): naive fp32 ----------------
__global__ void naive_kernel(const float* __restrict__ x, const float* __restrict__ w,
                             float* __restrict__ out) {
    int t = blockIdx.x;
    int o = blockIdx.y * 256 + threadIdx.x;
    const float* xr = x + (size_t)t * NCH;
    int r = o >> 6, oi = o & 63;
    float s = 0.f;
    for (int qq = 0; qq < 16; ++qq) {
        const float* wq = w + (r * 16 + qq) * 64;
        const float* xq = xr + qq * 64;
#pragma unroll 8
        for (int j = 0; j < 64; ++j) s += xq[j] * wq[(oi - j) & 63];
    }
    out[(size_t)t * NCH + o] = s;
}

extern "C" void kernel_launch(void* const* d_in, const int* in_sizes, int n_in,
                              void* d_out, int out_size, void* d_ws, size_t ws_size,
                              hipStream_t stream) {
    const float* x = (const float*)d_in[0];
    const float* w = (const float*)d_in[1];
    float* out = (float*)d_out;

    const size_t needW = (size_t)NCH * NCH * sizeof(unsigned short);   // 2 MB

    if (ws_size >= needW) {
        unsigned short* Wb = (unsigned short*)d_ws;
        hipLaunchKernelGGL(build_w_kernel, dim3(NCH * 128 / 256), dim3(256), 0, stream, w, Wb);
        hipLaunchKernelGGL(gemm_fused_kernel, dim3(2048), dim3(512), 0, stream, x, Wb, out);
    } else {
        hipLaunchKernelGGL(naive_kernel, dim3(NTOK, 4), dim3(256), 0, stream, x, w, out);
    }
}

// Round 16
// 108.789 us; speedup vs baseline: 1.2464x; 1.2464x over previous
//
#include <hip/hip_runtime.h>
#include <stdint.h>

// BCM_Linear: out = x @ W^T, W[o,k] = w[o>>6, k>>6, (o-k)&63]  (1024x1024)
// M=32768, N=1024, K=1024. bf16 MFMA compute, fp32 in/out.
// Round 16 (final config): R12 GEMM (best measured: distance-2 counted vmcnt,
// pre-swizzled xb/Wb, T1+T2+T5, 128x128/512thr/2blk-per-CU) + prep kernels
// MERGED into one dispatch (cvt_x and build_w share one grid).

#define NTOK 32768
#define NCH  1024
#define NKT  16

typedef short bf16x8 __attribute__((ext_vector_type(8)));
typedef float f32x4  __attribute__((ext_vector_type(4)));
typedef unsigned short u16x8 __attribute__((ext_vector_type(8)));

static __device__ __forceinline__ unsigned short f2bf(float f) {
    unsigned int u = __float_as_uint(f);
    u += 0x7FFFu + ((u >> 16) & 1u);
    return (unsigned short)(u >> 16);
}

#define GLOAD16(gp, lp)                                                          \
    __builtin_amdgcn_global_load_lds(                                            \
        (const __attribute__((address_space(1))) unsigned int*)(gp),             \
        (__attribute__((address_space(3))) unsigned int*)(lp), 16, 0, 0)

// ---------------- kernel 1: merged prep ----------------
// blocks [0, 16384): x fp32 -> bf16 pre-swizzled (R2/R4 proven form)
// blocks [16384, 16896): circulant w -> dense bf16 W pre-swizzled (proven)
#define XBLOCKS (NTOK * 128 / 256)   // 16384

__global__ void prep_kernel(const float* __restrict__ x, unsigned short* __restrict__ xb,
                            const float* __restrict__ w, unsigned short* __restrict__ Wb) {
    int b = blockIdx.x;
    if (b < XBLOCKS) {
        int i = b * 256 + threadIdx.x;            // 0 .. NTOK*128-1
        int row = i >> 7;
        int j   = i & 127;
        const float4* src = (const float4*)(x + (((size_t)row) << 10) + (j << 3));
        float4 a = src[0], c = src[1];
        u16x8 v;
        v[0]=f2bf(a.x); v[1]=f2bf(a.y); v[2]=f2bf(a.z); v[3]=f2bf(a.w);
        v[4]=f2bf(c.x); v[5]=f2bf(c.y); v[6]=f2bf(c.z); v[7]=f2bf(c.w);
        int js = (j & ~7) | ((j & 7) ^ (row & 7));
        *(u16x8*)(xb + (((size_t)row) << 10) + (js << 3)) = v;
    } else {
        int i = (b - XBLOCKS) * 256 + threadIdx.x;  // 0 .. 1024*128-1
        int o = i >> 7;
        int j = i & 127;
        int r = o >> 6;
        int q = j >> 3;
        const float* wrow = w + ((r * 16 + q) << 6);
        int k0 = j << 3;
        u16x8 v;
#pragma unroll
        for (int e = 0; e < 8; ++e) v[e] = f2bf(wrow[(o - (k0 + e)) & 63]);
        int js = (j & ~7) | ((j & 7) ^ (o & 7));
        *(u16x8*)(Wb + (((size_t)o) << 10) + (js << 3)) = v;
    }
}

// ---------------- kernel 2: 128x128 GEMM, distance-2 counted vmcnt (R12 verbatim) ----------------
#define BAR() __builtin_amdgcn_s_barrier()
#define LGKM0() asm volatile("s_waitcnt lgkmcnt(0)" ::: "memory")
#define VMCNT(n) asm volatile("s_waitcnt vmcnt(" #n ")" ::: "memory")
#define SETPRIO(n) __builtin_amdgcn_s_setprio(n)
#define MFMA4(d, av, bv) d = __builtin_amdgcn_mfma_f32_16x16x32_bf16(av, bv, d, 0, 0, 0)
#define NOHOOK ((void)0)

#define STAGE(bufA, bufB, t) do {                                                \
    const char* _sa = srcA + ((t) << 7);                                         \
    const char* _sb = srcB + ((t) << 7);                                         \
    char* _da = (bufA) + (wv << 10);                                             \
    char* _db = (bufB) + (wv << 10);                                             \
    GLOAD16(_sa, _da); GLOAD16(_sa + (64 << 11), _da + 8192);                    \
    GLOAD16(_sb, _db); GLOAD16(_sb + (64 << 11), _db + 8192);                    \
} while (0)

#define KSTEP2(Abuf, Bbuf, DO_STAGE, WN) do {                                    \
    bf16x8 afr[4][2], bfr[2][2];                                                 \
    _Pragma("unroll") for (int m = 0; m < 4; ++m)                                \
      _Pragma("unroll") for (int ks = 0; ks < 2; ++ks)                           \
        afr[m][ks] = *(const bf16x8*)((Abuf) + a_off[ks] + m * 2048);            \
    _Pragma("unroll") for (int n = 0; n < 2; ++n)                                \
      _Pragma("unroll") for (int ks = 0; ks < 2; ++ks)                           \
        bfr[n][ks] = *(const bf16x8*)((Bbuf) + b_off[ks] + n * 2048);            \
    LGKM0();                                                                     \
    BAR();                                                                       \
    DO_STAGE;                                                                    \
    SETPRIO(1);                                                                  \
    _Pragma("unroll") for (int m = 0; m < 4; ++m)                                \
      _Pragma("unroll") for (int n = 0; n < 2; ++n) {                            \
        MFMA4(acc[m][n], afr[m][0], bfr[n][0]);                                  \
        MFMA4(acc[m][n], afr[m][1], bfr[n][1]);                                  \
      }                                                                          \
    SETPRIO(0);                                                                  \
    WN;                                                                          \
    BAR();                                                                       \
} while (0)

__global__ void __launch_bounds__(512, 4) gemm128_kernel(const unsigned short* __restrict__ A,
                                                         const unsigned short* __restrict__ B,
                                                         float* __restrict__ C) {
    __shared__ __align__(16) char lds[65536];
    char* As0 = lds;
    char* As1 = lds + 16384;
    char* Bs0 = lds + 32768;
    char* Bs1 = lds + 49152;

    int tid  = threadIdx.x;
    int lane = tid & 63;
    int wv   = tid >> 6;
    int wr   = wv >> 2;        // 0..1  (M: 2 x 64 rows)
    int wc   = wv & 3;         // 0..3  (N: 4 x 32 cols)

    int cpx = gridDim.x >> 3;
    int wid = ((int)blockIdx.x & 7) * cpx + ((int)blockIdx.x >> 3);
    int tn = wid & 7, tm = wid >> 3;
    int m0 = tm * 128, n0 = tn * 128;

    const char* srcA = (const char*)A + (((size_t)(m0 + (tid >> 3))) << 11) + ((tid & 7) << 4);
    const char* srcB = (const char*)B + (((size_t)(n0 + (tid >> 3))) << 11) + ((tid & 7) << 4);

    int xa   = (lane & 7) << 4;
    int kq16 = (lane >> 4) << 4;
    int abase = (wr * 64 + (lane & 15)) * 128;
    int bbase = (wc * 32 + (lane & 15)) * 128;
    int a_off[2] = { abase + (kq16 ^ xa), abase + ((64 + kq16) ^ xa) };
    int b_off[2] = { bbase + (kq16 ^ xa), bbase + ((64 + kq16) ^ xa) };

    f32x4 acc[4][2] = {};

    STAGE(As0, Bs0, 0);
    STAGE(As1, Bs1, 1);
    VMCNT(4); BAR();

    for (int t = 0; t < 12; t += 2) {
        KSTEP2(As0, Bs0, STAGE(As0, Bs0, t + 2), VMCNT(4));
        KSTEP2(As1, Bs1, STAGE(As1, Bs1, t + 3), VMCNT(4));
    }
    KSTEP2(As0, Bs0, STAGE(As0, Bs0, 14), VMCNT(4));
    KSTEP2(As1, Bs1, STAGE(As1, Bs1, 15), VMCNT(4));
    KSTEP2(As0, Bs0, NOHOOK, VMCNT(0));
    {
        bf16x8 afr[4][2], bfr[2][2];
#pragma unroll
        for (int m = 0; m < 4; ++m)
#pragma unroll
            for (int ks = 0; ks < 2; ++ks)
                afr[m][ks] = *(const bf16x8*)(As1 + a_off[ks] + m * 2048);
#pragma unroll
        for (int n = 0; n < 2; ++n)
#pragma unroll
            for (int ks = 0; ks < 2; ++ks)
                bfr[n][ks] = *(const bf16x8*)(Bs1 + b_off[ks] + n * 2048);
        LGKM0();
        SETPRIO(1);
#pragma unroll
        for (int m = 0; m < 4; ++m)
#pragma unroll
            for (int n = 0; n < 2; ++n) {
                MFMA4(acc[m][n], afr[m][0], bfr[n][0]);
                MFMA4(acc[m][n], afr[m][1], bfr[n][1]);
            }
        SETPRIO(0);
    }

    float* Cp = C + ((size_t)(m0 + wr * 64)) * NCH + n0 + wc * 32;
    int cc = lane & 15;
    int rr = (lane >> 4) << 2;
#pragma unroll
    for (int m = 0; m < 4; ++m)
#pragma unroll
        for (int j = 0; j < 4; ++j) {
            float* rowp = Cp + ((size_t)(m * 16 + rr + j)) * NCH;
#pragma unroll
            for (int n = 0; n < 2; ++n)
                rowp[n * 16 + cc] = acc[m][n][j];
        }
}

// ---------------- fallback (ws too small): naive fp32 ----------------
__global__ void naive_kernel(const float* __restrict__ x, const float* __restrict__ w,
                             float* __restrict__ out) {
    int t = blockIdx.x;
    int o = blockIdx.y * 256 + threadIdx.x;
    const float* xr = x + (size_t)t * NCH;
    int r = o >> 6, oi = o & 63;
    float s = 0.f;
    for (int q = 0; q < 16; ++q) {
        const float* wq = w + (r * 16 + q) * 64;
        const float* xq = xr + q * 64;
#pragma unroll 8
        for (int j = 0; j < 64; ++j) s += xq[j] * wq[(oi - j) & 63];
    }
    out[(size_t)t * NCH + o] = s;
}

extern "C" void kernel_launch(void* const* d_in, const int* in_sizes, int n_in,
                              void* d_out, int out_size, void* d_ws, size_t ws_size,
                              hipStream_t stream) {
    const float* x = (const float*)d_in[0];
    const float* w = (const float*)d_in[1];
    float* out = (float*)d_out;

    const size_t needX = (size_t)NTOK * NCH * sizeof(unsigned short);  // 64 MB
    const size_t needW = (size_t)NCH * NCH * sizeof(unsigned short);   //  2 MB

    if (ws_size >= needX + needW) {
        unsigned short* xb = (unsigned short*)d_ws;
        unsigned short* Wb = (unsigned short*)((char*)d_ws + needX);
        hipLaunchKernelGGL(prep_kernel, dim3(XBLOCKS + NCH * 128 / 256), dim3(256), 0, stream,
                           x, xb, w, Wb);
        hipLaunchKernelGGL(gemm128_kernel, dim3(2048), dim3(512), 0, stream, xb, Wb, out);
    } else {
        hipLaunchKernelGGL(naive_kernel, dim3(NTOK, 4), dim3(256), 0, stream, x, w, out);
    }
}